// Round 12
// baseline (183.253 us; speedup 1.0000x reference)
//
#include <hip/hip_runtime.h>
#include <hip/hip_fp16.h>

#define NF   128
#define C1   16
#define C2   32
#define NCLS 10
#define BSH  8          // bucket = 256 nodes
#define BN   256
#define MAXB 512        // hist array size >= nbuck+1 = 392
#define S    9216       // csr stride per bucket (mean 8192, +11 sigma)
#define TILE 2048       // edges per bin block
#define EPT  (TILE/256)
#define NRUN 2048       // >= nblkA = 1563

// ============ Phase A: per-block bucket grouping, direct write to own segment ============

__global__ __launch_bounds__(256) void k_bin(const int* __restrict__ ei,
                                             int* __restrict__ packed,
                                             int* __restrict__ offmat,
                                             int E, int nbuck) {
    __shared__ int hist[MAXB];
    __shared__ int off0[MAXB];
    __shared__ int cur[MAXB];
    int tid = threadIdx.x;
    long long t0 = (long long)blockIdx.x * TILE;

    for (int i = tid; i < MAXB; i += 256) hist[i] = 0;
    __syncthreads();

    int dstv[EPT], srcv[EPT];
#pragma unroll
    for (int u = 0; u < EPT; ++u) {
        long long e = t0 + tid + u * 256;
        int d = -1, s = 0;
        if (e < E) { d = ei[E + e]; s = ei[e]; }
        dstv[u] = d; srcv[u] = s;
        if (d >= 0) atomicAdd(&hist[d >> BSH], 1);
    }
    __syncthreads();
    // exclusive scan of hist[0..MAXB) by wave 0 (cross-chunk carry included)
    if (tid < 64) {
        int carry = 0;
        for (int c = 0; c < MAXB / 64; ++c) {
            int idx = c * 64 + tid;
            int v = hist[idx];
            int orig = v;
            for (int off = 1; off < 64; off <<= 1) {
                int t = __shfl_up(v, off);
                if (tid >= off) v += t;
            }
            int ex = v - orig + carry;
            off0[idx] = ex;
            cur[idx] = ex;
            carry += __shfl(v, 63);
        }
    }
    __syncthreads();
    int* orow = offmat + (size_t)blockIdx.x * (nbuck + 1);
    for (int b = tid; b <= nbuck; b += 256) orow[b] = off0[b];
#pragma unroll
    for (int u = 0; u < EPT; ++u) {
        int d = dstv[u];
        if (d >= 0) {
            int b = d >> BSH;
            int slot = atomicAdd(&cur[b], 1);
            packed[t0 + slot] = srcv[u] | ((d & (BN - 1)) << 17);
        }
    }
}

// ============ Phase B: one 1024-thread block per bucket, stage-less ============
// 2-chunk run scan -> (binary search + read) x2 passes -> csr/rowptr/deg/dinv + y1h scale

__global__ __launch_bounds__(1024) void k_csr(const int* __restrict__ packed,
                                              const int* __restrict__ offmat,
                                              int* __restrict__ csr,
                                              int* __restrict__ rowptr,
                                              int* __restrict__ deg,
                                              float* __restrict__ dinv,
                                              __half* __restrict__ y1h,
                                              int N, int nbuck, int nblkA) {
    __shared__ int startA[NRUN];   // 8 KB (inclusive scan -> exclusive starts)
    __shared__ int o1A[NRUN];      // 8 KB
    __shared__ int hcnt[BN];
    __shared__ int sh2[BN];
    __shared__ int cur[BN];
    __shared__ float fdinv[BN];
    int tid = threadIdx.x;
    int b = blockIdx.x;
    size_t base = (size_t)b * S;

    int len0 = 0, len1 = 0;
    {
        int o = 0, L = 0;
        if (tid < nblkA) {
            const int* orow = offmat + (size_t)tid * (nbuck + 1) + b;
            o = orow[0]; L = orow[1] - o;
        }
        o1A[tid] = o; startA[tid] = L; len0 = L;
    }
    {
        int idx = 1024 + tid, o = 0, L = 0;
        if (idx < nblkA) {
            const int* orow = offmat + (size_t)idx * (nbuck + 1) + b;
            o = orow[0]; L = orow[1] - o;
        }
        o1A[idx] = o; startA[idx] = L; len1 = L;
    }
    if (tid < BN) hcnt[tid] = 0;
    __syncthreads();
    // independent inclusive scans of the two 1024-chunks
    for (int off = 1; off < 1024; off <<= 1) {
        int a0 = (tid >= off) ? startA[tid - off] : 0;
        int a1 = (tid >= off) ? startA[1024 + tid - off] : 0;
        __syncthreads();
        if (tid >= off) { startA[tid] += a0; startA[1024 + tid] += a1; }
        __syncthreads();
    }
    int c0 = startA[1023];             // chunk-0 total (not written below)
    startA[1024 + tid] += c0;          // stitch chunk 1
    __syncthreads();
    int m = startA[NRUN - 1];          // bucket edge count
    int e0 = startA[tid] - len0;       // inclusive -> exclusive
    int e1 = startA[1024 + tid] - len1;
    __syncthreads();
    startA[tid] = e0;
    startA[1024 + tid] = e1;
    __syncthreads();

    // pass 1: histogram (coalesced reads via run binary search)
    for (int i = tid; i < m; i += 1024) {
        int lo = 0, hi = NRUN - 1;
        while (lo < hi) {              // largest j with startA[j] <= i
            int mid = (lo + hi + 1) >> 1;
            if (startA[mid] <= i) lo = mid; else hi = mid - 1;
        }
        int p = packed[(size_t)lo * TILE + o1A[lo] + (i - startA[lo])];
        atomicAdd(&hcnt[p >> 17], 1);
    }
    __syncthreads();
    // scan hcnt (256 entries, unconditional barriers)
    int v = 0;
    if (tid < BN) { v = hcnt[tid]; sh2[tid] = v; }
    __syncthreads();
    for (int off = 1; off < BN; off <<= 1) {
        int t = (tid < BN && tid >= off) ? sh2[tid - off] : 0;
        __syncthreads();
        if (tid < BN) sh2[tid] += t;
        __syncthreads();
    }
    if (tid < BN) {
        int ex = sh2[tid] - v;
        cur[tid] = ex;
        float dv = rsqrtf((float)v + 1.0f);   // +1 self-loop
        fdinv[tid] = dv;
        int n = (b << BSH) + tid;
        if (n < N) {
            rowptr[n] = (int)base + ex;
            deg[n] = v;
            dinv[n] = dv;
        }
    }
    __syncthreads();
    // pass 2: place (re-read, L2-hot)
    for (int i = tid; i < m; i += 1024) {
        int lo = 0, hi = NRUN - 1;
        while (lo < hi) {
            int mid = (lo + hi + 1) >> 1;
            if (startA[mid] <= i) lo = mid; else hi = mid - 1;
        }
        int p = packed[(size_t)lo * TILE + o1A[lo] + (i - startA[lo])];
        int slot = atomicAdd(&cur[p >> 17], 1);
        csr[base + slot] = p & 0x1FFFF;
    }
    // scale this bucket's y1h rows by dinv
    int n0 = b << BSH;
    int lim = min(BN, N - n0);
    if (lim > 0) {
        __half2* yrow = (__half2*)y1h + (size_t)n0 * 8;
        int tot = lim * 8;
        for (int i = tid; i < tot; i += 1024) {
            float dv = fdinv[i >> 3];
            float2 f = __half22float2(yrow[i]);
            yrow[i] = __floats2half2_rn(f.x * dv, f.y * dv);
        }
    }
}

// ============ linear 1: y1h = half(x @ W1)  (dinv scale applied in k_csr) ============

__global__ __launch_bounds__(256) void k_lin1(const float* __restrict__ x,
                                              const float* __restrict__ W1,
                                              __half* __restrict__ y1h, int N) {
    __shared__ float ws[NF * C1];
    __shared__ float xs[16 * 132];
    int tid = threadIdx.x;
    for (int t = tid; t < NF * C1; t += 256) ws[t] = W1[t];
    int n0 = blockIdx.x * 16;
    const float4* x4 = (const float4*)x;
    for (int t = tid; t < 16 * 32; t += 256) {
        int r = t >> 5, c = t & 31;
        int n = n0 + r;
        float4 v = (n < N) ? x4[(size_t)n * 32 + c] : make_float4(0.f, 0.f, 0.f, 0.f);
        float* d = &xs[r * 132 + c * 4];
        d[0] = v.x; d[1] = v.y; d[2] = v.z; d[3] = v.w;
    }
    __syncthreads();
    int r = tid >> 4, j = tid & 15;
    float acc = 0.0f;
#pragma unroll 4
    for (int k = 0; k < NF; ++k) acc += xs[r * 132 + k] * ws[k * C1 + j];
    int n = n0 + r;
    if (n < N) y1h[(size_t)n * C1 + j] = __float2half_rn(acc);
}

// ============ fp16 gather (16-dim, f32 accum), 4 threads/node, 8B loads ============
// MODE 0: out = float4 agg = dinv*(self + sum)          (feeds pool_fc)
// MODE 1: out = 4x half  u  = relu(agg + b1)*dinv       (feeds 2nd gather)

template <int MODE>
__global__ __launch_bounds__(256) void k_gather_h(const int* __restrict__ rowptr,
                                                  const int* __restrict__ deg,
                                                  const int* __restrict__ csr,
                                                  const float* __restrict__ dinv,
                                                  const float* __restrict__ bias,
                                                  const uint2* __restrict__ yh,
                                                  void* __restrict__ outp, int N) {
    int tid = threadIdx.x;
    int j = tid & 3;                       // quarter-row (4 halfs)
    int n = blockIdx.x * 64 + (tid >> 2);
    if (n >= N) return;
    int k0 = rowptr[n];
    int k1 = k0 + deg[n];
    union U { uint2 u; __half2 h[2]; };
    U su; su.u = yh[(size_t)n * 4 + j];
    float2 sl = __half22float2(su.h[0]), shh = __half22float2(su.h[1]);
    float a0 = sl.x, a1 = sl.y, a2 = shh.x, a3 = shh.y;
    float b0 = 0.f, b1v = 0.f, b2 = 0.f, b3 = 0.f;
    int k = k0;
    for (; k + 3 < k1; k += 4) {
        int s0 = csr[k], s1 = csr[k + 1], s2 = csr[k + 2], s3 = csr[k + 3];
        U v0, v1, v2, v3;
        v0.u = yh[(size_t)s0 * 4 + j];
        v1.u = yh[(size_t)s1 * 4 + j];
        v2.u = yh[(size_t)s2 * 4 + j];
        v3.u = yh[(size_t)s3 * 4 + j];
        float2 l0 = __half22float2(v0.h[0]), h0 = __half22float2(v0.h[1]);
        float2 l1 = __half22float2(v1.h[0]), h1 = __half22float2(v1.h[1]);
        float2 l2 = __half22float2(v2.h[0]), h2 = __half22float2(v2.h[1]);
        float2 l3 = __half22float2(v3.h[0]), h3 = __half22float2(v3.h[1]);
        a0 += l0.x; a1 += l0.y; a2 += h0.x; a3 += h0.y;
        b0 += l1.x; b1v += l1.y; b2 += h1.x; b3 += h1.y;
        a0 += l2.x; a1 += l2.y; a2 += h2.x; a3 += h2.y;
        b0 += l3.x; b1v += l3.y; b2 += h3.x; b3 += h3.y;
    }
    for (; k < k1; ++k) {
        U v; v.u = yh[(size_t)csr[k] * 4 + j];
        float2 l = __half22float2(v.h[0]), h = __half22float2(v.h[1]);
        a0 += l.x; a1 += l.y; a2 += h.x; a3 += h.y;
    }
    float dn = dinv[n];
    float r0 = dn * (a0 + b0), r1 = dn * (a1 + b1v);
    float r2 = dn * (a2 + b2), r3 = dn * (a3 + b3);
    if (MODE == 0) {
        ((float4*)outp)[(size_t)n * 4 + j] = make_float4(r0, r1, r2, r3);
    } else {
        float4 bb = ((const float4*)bias)[j];
        U o;
        o.h[0] = __floats2half2_rn(fmaxf(r0 + bb.x, 0.0f) * dn, fmaxf(r1 + bb.y, 0.0f) * dn);
        o.h[1] = __floats2half2_rn(fmaxf(r2 + bb.z, 0.0f) * dn, fmaxf(r3 + bb.w, 0.0f) * dn);
        ((uint2*)outp)[(size_t)n * 4 + j] = o.u;
    }
}

// ============ pool + W2 + relu + FC fused (per graph; sorted batch) ============

__global__ __launch_bounds__(256) void k_pool_fc(const float* __restrict__ z,
                                                 const float* __restrict__ W2,
                                                 const float* __restrict__ b2,
                                                 const int* __restrict__ batch,
                                                 const float* __restrict__ Wfc,
                                                 const float* __restrict__ bfc,
                                                 float* __restrict__ out, int N, int G) {
    __shared__ float W2s[C1 * C2];
    int tid = threadIdx.x;
    for (int t = tid; t < C1 * C2; t += 256) W2s[t] = W2[t];

    int g = blockIdx.x;
    int lo = 0, hi = N;
    while (lo < hi) { int m = (lo + hi) >> 1; if (batch[m] < g) lo = m + 1; else hi = m; }
    int start = lo;
    lo = start; hi = N;
    while (lo < hi) { int m = (lo + hi) >> 1; if (batch[m] < g + 1) lo = m + 1; else hi = m; }
    int end = lo;
    __syncthreads();

    int i = tid & 31, r = tid >> 5;       // 8 node-groups x 32 output channels
    float bi = b2[i];
    float acc = 0.0f;
    for (int n = start + r; n < end; n += 8) {
        const float* zr = &z[(size_t)n * C1];
        float h = bi;
#pragma unroll
        for (int j = 0; j < C1; ++j) h += zr[j] * W2s[j * C2 + i];
        acc += fmaxf(h, 0.0f);
    }

    __shared__ float red[256];
    red[tid] = acc;
    __syncthreads();
    for (int s = 4; s >= 1; s >>= 1) {
        if (r < s) red[tid] += red[tid + s * 32];
        __syncthreads();
    }
    __shared__ float pooled[C2];
    if (tid < C2) {
        float cnt = (float)(end - start);
        pooled[tid] = red[tid] / fmaxf(cnt, 1.0f);
    }
    __syncthreads();
    if (tid < NCLS) {
        float a = bfc[tid];
#pragma unroll
        for (int j = 0; j < C2; ++j) a += pooled[j] * Wfc[j * NCLS + tid];
        out[g * NCLS + tid] = a;
    }
}

extern "C" void kernel_launch(void* const* d_in, const int* in_sizes, int n_in,
                              void* d_out, int out_size, void* d_ws, size_t ws_size,
                              hipStream_t stream) {
    const float* x    = (const float*)d_in[0];
    const int*   ei   = (const int*)d_in[1];
    const int*   batch= (const int*)d_in[2];
    const float* W1   = (const float*)d_in[3];
    const float* b1   = (const float*)d_in[4];
    const float* W2   = (const float*)d_in[5];
    const float* b2   = (const float*)d_in[6];
    const float* Wfc  = (const float*)d_in[7];
    const float* bfc  = (const float*)d_in[8];
    float* out = (float*)d_out;

    const int N = in_sizes[0] / NF;          // 100000
    const int E = in_sizes[1] / 2;           // 3200000
    const int G = out_size / NCLS;           // 256
    const int nbuck = (N + BN - 1) >> BSH;   // 391
    const int nblkA = (E + TILE - 1) / TILE; // 1563

    char* p = (char*)d_ws;
    auto alloc = [&](size_t bytes) { char* q = p; p += (bytes + 63) & ~(size_t)63; return q; };
    int*     rowptr  = (int*)    alloc((size_t)N * 4);
    int*     deg     = (int*)    alloc((size_t)N * 4);
    float*   dinv    = (float*)  alloc((size_t)N * 4);
    int*     packed  = (int*)    alloc((size_t)nblkA * TILE * 4);         // 12.8 MB
    int*     offmat  = (int*)    alloc((size_t)nblkA * (nbuck + 1) * 4); // 2.45 MB
    int*     csr     = (int*)    alloc((size_t)nbuck * S * 4);           // 14.4 MB
    __half*  y1h     = (__half*) alloc((size_t)N * C1 * 2);
    __half*  uh      = (__half*) alloc((size_t)N * C1 * 2);
    float*   z       = (float*)  alloc((size_t)N * C1 * 4);

    const int B = 256;

    // --- CSR build ---
    k_bin<<<nblkA, B, 0, stream>>>(ei, packed, offmat, E, nbuck);
    k_lin1<<<(N + 15) / 16, B, 0, stream>>>(x, W1, y1h, N);
    k_csr<<<nbuck, 1024, 0, stream>>>(packed, offmat, csr, rowptr, deg, dinv, y1h,
                                      N, nbuck, nblkA);

    // --- layer 1 aggregation + fused relu/b1/dinv epilogue ---
    k_gather_h<1><<<(N + 63) / 64, B, 0, stream>>>(rowptr, deg, csr, dinv, b1,
                                                   (const uint2*)y1h, uh, N);
    // --- layer 2 aggregation (16-dim; W2 commuted into pool) ---
    k_gather_h<0><<<(N + 63) / 64, B, 0, stream>>>(rowptr, deg, csr, dinv, b1,
                                                   (const uint2*)uh, z, N);

    // --- pool + W2 + relu + FC ---
    k_pool_fc<<<G, B, 0, stream>>>(z, W2, b2, batch, Wfc, bfc, out, N, G);
}

// Round 13
// 176.179 us; speedup vs baseline: 1.0402x; 1.0402x over previous
//
#include <hip/hip_runtime.h>
#include <hip/hip_fp16.h>

#define NF   128
#define C1   16
#define C2   32
#define NCLS 10
#define BSH  8          // bucket = 256 nodes
#define BN   256
#define MAXB 512        // hist array size >= nbuck+1 = 392
#define S    9216       // csr stride per bucket (mean 8192, +11 sigma)
#define TILE 4096       // edges per bin block (runs ~10 edges; don't shrink — R11 lesson)
#define EPT  (TILE/256)
#define CAP  12288      // LDS stage capacity in k_csr (mean 8192, +45 sigma)

// ============ Phase A: per-block bucket grouping, direct write to own segment ============
// packed[t0 + slot] = src | (local_dst << 17); offmat[blk][b] = run start in segment

__global__ __launch_bounds__(256) void k_bin(const int* __restrict__ ei,
                                             int* __restrict__ packed,
                                             int* __restrict__ offmat,
                                             int E, int nbuck) {
    __shared__ int hist[MAXB];
    __shared__ int off0[MAXB];
    __shared__ int cur[MAXB];
    int tid = threadIdx.x;
    long long t0 = (long long)blockIdx.x * TILE;

    for (int i = tid; i < MAXB; i += 256) hist[i] = 0;
    __syncthreads();

    int dstv[EPT], srcv[EPT];
#pragma unroll
    for (int u = 0; u < EPT; ++u) {
        long long e = t0 + tid + u * 256;
        int d = -1, s = 0;
        if (e < E) { d = ei[E + e]; s = ei[e]; }
        dstv[u] = d; srcv[u] = s;
        if (d >= 0) atomicAdd(&hist[d >> BSH], 1);
    }
    __syncthreads();
    // exclusive scan of hist[0..MAXB) by wave 0 (cross-chunk carry included)
    if (tid < 64) {
        int carry = 0;
        for (int c = 0; c < MAXB / 64; ++c) {
            int idx = c * 64 + tid;
            int v = hist[idx];
            int orig = v;
            for (int off = 1; off < 64; off <<= 1) {
                int t = __shfl_up(v, off);
                if (tid >= off) v += t;
            }
            int ex = v - orig + carry;
            off0[idx] = ex;
            cur[idx] = ex;
            carry += __shfl(v, 63);
        }
    }
    __syncthreads();
    int* orow = offmat + (size_t)blockIdx.x * (nbuck + 1);
    for (int b = tid; b <= nbuck; b += 256) orow[b] = off0[b];
#pragma unroll
    for (int u = 0; u < EPT; ++u) {
        int d = dstv[u];
        if (d >= 0) {
            int b = d >> BSH;
            int slot = atomicAdd(&cur[b], 1);
            packed[t0 + slot] = srcv[u] | ((d & (BN - 1)) << 17);
        }
    }
}

// ============ Phase B: one 1024-thread block per bucket (staged) ============
// run-gather (binary search) -> LDS stage -> counting sort -> csr/rowptr/deg/dinv

__global__ __launch_bounds__(1024) void k_csr(const int* __restrict__ packed,
                                              const int* __restrict__ offmat,
                                              int* __restrict__ csr,
                                              int* __restrict__ rowptr,
                                              int* __restrict__ deg,
                                              float* __restrict__ dinv,
                                              int N, int nbuck, int nblkA) {
    __shared__ int stage[CAP];      // 48 KB
    __shared__ int startA[1024];
    __shared__ int spsA[1024];
    __shared__ int o1A[1024];
    __shared__ int hcnt[BN];
    __shared__ int sh[BN];
    __shared__ int cur[BN];
    int tid = threadIdx.x;
    int b = blockIdx.x;
    size_t base = (size_t)b * S;

    int len = 0, o1 = 0;
    if (tid < nblkA) {
        const int* orow = offmat + (size_t)tid * (nbuck + 1) + b;
        o1 = orow[0];
        len = orow[1] - o1;
    }
    o1A[tid] = o1;
    spsA[tid] = len;
    if (tid < BN) hcnt[tid] = 0;
    __syncthreads();
    // inclusive scan of run lengths
    for (int off = 1; off < 1024; off <<= 1) {
        int t = (tid >= off) ? spsA[tid - off] : 0;
        __syncthreads();
        spsA[tid] += t;
        __syncthreads();
    }
    int m = spsA[1023];
    startA[tid] = spsA[tid] - len;
    __syncthreads();
    if (m > CAP) m = CAP;   // statistically impossible; prevents LDS OOB

    // thread-per-edge coalesced gather + histogram
    for (int i = tid; i < m; i += 1024) {
        int lo = 0, hi = 1023;
        while (lo < hi) {      // largest j with startA[j] <= i
            int mid = (lo + hi + 1) >> 1;
            if (startA[mid] <= i) lo = mid; else hi = mid - 1;
        }
        int p = packed[(size_t)lo * TILE + o1A[lo] + (i - startA[lo])];
        stage[i] = p;
        atomicAdd(&hcnt[p >> 17], 1);
    }
    __syncthreads();
    // scan hcnt (256 entries; unconditional barriers)
    int v = 0;
    if (tid < BN) { v = hcnt[tid]; sh[tid] = v; }
    __syncthreads();
    for (int off = 1; off < BN; off <<= 1) {
        int t = (tid < BN && tid >= off) ? sh[tid - off] : 0;
        __syncthreads();
        if (tid < BN) sh[tid] += t;
        __syncthreads();
    }
    if (tid < BN) {
        int ex = sh[tid] - v;
        cur[tid] = ex;
        int n = (b << BSH) + tid;
        if (n < N) {
            rowptr[n] = (int)base + ex;
            deg[n] = v;
            dinv[n] = rsqrtf((float)v + 1.0f);   // +1 self-loop
        }
    }
    __syncthreads();
    // place
    for (int i = tid; i < m; i += 1024) {
        int p = stage[i];
        int slot = atomicAdd(&cur[p >> 17], 1);
        csr[base + slot] = p & 0x1FFFF;
    }
}

// ============ linear 1: y1h = half((x @ W1) * dinv)  [N,16] fp16 ============

__global__ __launch_bounds__(256) void k_lin1(const float* __restrict__ x,
                                              const float* __restrict__ W1,
                                              const float* __restrict__ dinv,
                                              __half* __restrict__ y1h, int N) {
    __shared__ float ws[NF * C1];
    __shared__ float xs[16 * 132];
    int tid = threadIdx.x;
    for (int t = tid; t < NF * C1; t += 256) ws[t] = W1[t];
    int n0 = blockIdx.x * 16;
    const float4* x4 = (const float4*)x;
    for (int t = tid; t < 16 * 32; t += 256) {
        int r = t >> 5, c = t & 31;
        int n = n0 + r;
        float4 v = (n < N) ? x4[(size_t)n * 32 + c] : make_float4(0.f, 0.f, 0.f, 0.f);
        float* d = &xs[r * 132 + c * 4];
        d[0] = v.x; d[1] = v.y; d[2] = v.z; d[3] = v.w;
    }
    __syncthreads();
    int r = tid >> 4, j = tid & 15;
    float acc = 0.0f;
#pragma unroll 4
    for (int k = 0; k < NF; ++k) acc += xs[r * 132 + k] * ws[k * C1 + j];
    int n = n0 + r;
    if (n < N) y1h[(size_t)n * C1 + j] = __float2half_rn(acc * dinv[n]);
}

// ============ fp16 gather (16-dim, f32 accum), 4 threads/node, 8B loads ============
// MODE 0: out = float4 agg = dinv*(self + sum)          (feeds pool_fc)
// MODE 1: out = 4x half  u  = relu(agg + b1)*dinv       (feeds 2nd gather)

template <int MODE>
__global__ __launch_bounds__(256) void k_gather_h(const int* __restrict__ rowptr,
                                                  const int* __restrict__ deg,
                                                  const int* __restrict__ csr,
                                                  const float* __restrict__ dinv,
                                                  const float* __restrict__ bias,
                                                  const uint2* __restrict__ yh,
                                                  void* __restrict__ outp, int N) {
    int tid = threadIdx.x;
    int j = tid & 3;                       // quarter-row (4 halfs)
    int n = blockIdx.x * 64 + (tid >> 2);
    if (n >= N) return;
    int k0 = rowptr[n];
    int k1 = k0 + deg[n];
    union U { uint2 u; __half2 h[2]; };
    U su; su.u = yh[(size_t)n * 4 + j];
    float2 sl = __half22float2(su.h[0]), shh = __half22float2(su.h[1]);
    float a0 = sl.x, a1 = sl.y, a2 = shh.x, a3 = shh.y;
    float b0 = 0.f, b1v = 0.f, b2 = 0.f, b3 = 0.f;
    int k = k0;
    for (; k + 3 < k1; k += 4) {
        int s0 = csr[k], s1 = csr[k + 1], s2 = csr[k + 2], s3 = csr[k + 3];
        U v0, v1, v2, v3;
        v0.u = yh[(size_t)s0 * 4 + j];
        v1.u = yh[(size_t)s1 * 4 + j];
        v2.u = yh[(size_t)s2 * 4 + j];
        v3.u = yh[(size_t)s3 * 4 + j];
        float2 l0 = __half22float2(v0.h[0]), h0 = __half22float2(v0.h[1]);
        float2 l1 = __half22float2(v1.h[0]), h1 = __half22float2(v1.h[1]);
        float2 l2 = __half22float2(v2.h[0]), h2 = __half22float2(v2.h[1]);
        float2 l3 = __half22float2(v3.h[0]), h3 = __half22float2(v3.h[1]);
        a0 += l0.x; a1 += l0.y; a2 += h0.x; a3 += h0.y;
        b0 += l1.x; b1v += l1.y; b2 += h1.x; b3 += h1.y;
        a0 += l2.x; a1 += l2.y; a2 += h2.x; a3 += h2.y;
        b0 += l3.x; b1v += l3.y; b2 += h3.x; b3 += h3.y;
    }
    for (; k < k1; ++k) {
        U v; v.u = yh[(size_t)csr[k] * 4 + j];
        float2 l = __half22float2(v.h[0]), h = __half22float2(v.h[1]);
        a0 += l.x; a1 += l.y; a2 += h.x; a3 += h.y;
    }
    float dn = dinv[n];
    float r0 = dn * (a0 + b0), r1 = dn * (a1 + b1v);
    float r2 = dn * (a2 + b2), r3 = dn * (a3 + b3);
    if (MODE == 0) {
        ((float4*)outp)[(size_t)n * 4 + j] = make_float4(r0, r1, r2, r3);
    } else {
        float4 bb = ((const float4*)bias)[j];
        U o;
        o.h[0] = __floats2half2_rn(fmaxf(r0 + bb.x, 0.0f) * dn, fmaxf(r1 + bb.y, 0.0f) * dn);
        o.h[1] = __floats2half2_rn(fmaxf(r2 + bb.z, 0.0f) * dn, fmaxf(r3 + bb.w, 0.0f) * dn);
        ((uint2*)outp)[(size_t)n * 4 + j] = o.u;
    }
}

// ============ pool + W2 + relu + FC fused (per graph; sorted batch) ============

__global__ __launch_bounds__(256) void k_pool_fc(const float* __restrict__ z,
                                                 const float* __restrict__ W2,
                                                 const float* __restrict__ b2,
                                                 const int* __restrict__ batch,
                                                 const float* __restrict__ Wfc,
                                                 const float* __restrict__ bfc,
                                                 float* __restrict__ out, int N, int G) {
    __shared__ float W2s[C1 * C2];
    int tid = threadIdx.x;
    for (int t = tid; t < C1 * C2; t += 256) W2s[t] = W2[t];

    int g = blockIdx.x;
    int lo = 0, hi = N;
    while (lo < hi) { int m = (lo + hi) >> 1; if (batch[m] < g) lo = m + 1; else hi = m; }
    int start = lo;
    lo = start; hi = N;
    while (lo < hi) { int m = (lo + hi) >> 1; if (batch[m] < g + 1) lo = m + 1; else hi = m; }
    int end = lo;
    __syncthreads();

    int i = tid & 31, r = tid >> 5;       // 8 node-groups x 32 output channels
    float bi = b2[i];
    float acc = 0.0f;
    for (int n = start + r; n < end; n += 8) {
        const float* zr = &z[(size_t)n * C1];
        float h = bi;
#pragma unroll
        for (int j = 0; j < C1; ++j) h += zr[j] * W2s[j * C2 + i];
        acc += fmaxf(h, 0.0f);
    }

    __shared__ float red[256];
    red[tid] = acc;
    __syncthreads();
    for (int s = 4; s >= 1; s >>= 1) {
        if (r < s) red[tid] += red[tid + s * 32];
        __syncthreads();
    }
    __shared__ float pooled[C2];
    if (tid < C2) {
        float cnt = (float)(end - start);
        pooled[tid] = red[tid] / fmaxf(cnt, 1.0f);
    }
    __syncthreads();
    if (tid < NCLS) {
        float a = bfc[tid];
#pragma unroll
        for (int j = 0; j < C2; ++j) a += pooled[j] * Wfc[j * NCLS + tid];
        out[g * NCLS + tid] = a;
    }
}

extern "C" void kernel_launch(void* const* d_in, const int* in_sizes, int n_in,
                              void* d_out, int out_size, void* d_ws, size_t ws_size,
                              hipStream_t stream) {
    const float* x    = (const float*)d_in[0];
    const int*   ei   = (const int*)d_in[1];
    const int*   batch= (const int*)d_in[2];
    const float* W1   = (const float*)d_in[3];
    const float* b1   = (const float*)d_in[4];
    const float* W2   = (const float*)d_in[5];
    const float* b2   = (const float*)d_in[6];
    const float* Wfc  = (const float*)d_in[7];
    const float* bfc  = (const float*)d_in[8];
    float* out = (float*)d_out;

    const int N = in_sizes[0] / NF;          // 100000
    const int E = in_sizes[1] / 2;           // 3200000
    const int G = out_size / NCLS;           // 256
    const int nbuck = (N + BN - 1) >> BSH;   // 391
    const int nblkA = (E + TILE - 1) / TILE; // 782

    char* p = (char*)d_ws;
    auto alloc = [&](size_t bytes) { char* q = p; p += (bytes + 63) & ~(size_t)63; return q; };
    int*     rowptr  = (int*)    alloc((size_t)N * 4);
    int*     deg     = (int*)    alloc((size_t)N * 4);
    float*   dinv    = (float*)  alloc((size_t)N * 4);
    int*     packed  = (int*)    alloc((size_t)nblkA * TILE * 4);         // 12.8 MB
    int*     offmat  = (int*)    alloc((size_t)nblkA * (nbuck + 1) * 4); // 1.2 MB
    int*     csr     = (int*)    alloc((size_t)nbuck * S * 4);           // 14.4 MB
    __half*  y1h     = (__half*) alloc((size_t)N * C1 * 2);
    __half*  uh      = (__half*) alloc((size_t)N * C1 * 2);
    float*   z       = (float*)  alloc((size_t)N * C1 * 4);

    const int B = 256;

    // --- CSR build: tile-local grouping (coalesced) + staged run-gather sort ---
    k_bin<<<nblkA, B, 0, stream>>>(ei, packed, offmat, E, nbuck);
    k_csr<<<nbuck, 1024, 0, stream>>>(packed, offmat, csr, rowptr, deg, dinv,
                                      N, nbuck, nblkA);

    // --- layer 1 ---
    k_lin1<<<(N + 15) / 16, B, 0, stream>>>(x, W1, dinv, y1h, N);
    k_gather_h<1><<<(N + 63) / 64, B, 0, stream>>>(rowptr, deg, csr, dinv, b1,
                                                   (const uint2*)y1h, uh, N);
    // --- layer 2 aggregation (16-dim; W2 commuted into pool) ---
    k_gather_h<0><<<(N + 63) / 64, B, 0, stream>>>(rowptr, deg, csr, dinv, b1,
                                                   (const uint2*)uh, z, N);

    // --- pool + W2 + relu + FC ---
    k_pool_fc<<<G, B, 0, stream>>>(z, W2, b2, batch, Wfc, bfc, out, N, G);
}

// Round 14
// 171.599 us; speedup vs baseline: 1.0679x; 1.0267x over previous
//
#include <hip/hip_runtime.h>
#include <hip/hip_fp16.h>

#define NF   128
#define C1   16
#define C2   32
#define NCLS 10
#define BSH  8          // bucket = 256 nodes
#define BN   256
#define MAXB 512        // hist array size >= nbuck+1 = 392
#define S    9216       // csr stride per bucket (mean 8192, +11 sigma)
#define TILE 4096       // edges per bin block (runs ~10 edges; don't shrink — R11 lesson)
#define CAP  12288      // LDS stage capacity in k_csr (mean 8192, +45 sigma)

// ============ Phase A: per-block bucket grouping, direct write to own segment ============
// 512 threads, 8 consecutive edges/thread via int4 loads.
// packed[t0 + slot] = src | (local_dst << 17); offmat[blk][b] = run start in segment

__global__ __launch_bounds__(512) void k_bin(const int* __restrict__ ei,
                                             int* __restrict__ packed,
                                             int* __restrict__ offmat,
                                             int E, int nbuck) {
    __shared__ int hist[MAXB];
    __shared__ int off0[MAXB];
    __shared__ int cur[MAXB];
    int tid = threadIdx.x;
    long long t0 = (long long)blockIdx.x * TILE;

    for (int i = tid; i < MAXB; i += 512) hist[i] = 0;
    __syncthreads();

    long long eb = t0 + (long long)tid * 8;
    int src[8], dst[8];
    if (eb + 8 <= E) {
        const int4* s4 = (const int4*)(ei + eb);
        const int4* d4 = (const int4*)(ei + E + eb);
        int4 a = s4[0], b = s4[1], c = d4[0], d = d4[1];
        src[0]=a.x; src[1]=a.y; src[2]=a.z; src[3]=a.w;
        src[4]=b.x; src[5]=b.y; src[6]=b.z; src[7]=b.w;
        dst[0]=c.x; dst[1]=c.y; dst[2]=c.z; dst[3]=c.w;
        dst[4]=d.x; dst[5]=d.y; dst[6]=d.z; dst[7]=d.w;
    } else {
#pragma unroll
        for (int u = 0; u < 8; ++u) {
            long long e = eb + u;
            src[u] = (e < E) ? ei[e] : 0;
            dst[u] = (e < E) ? ei[E + e] : -1;
        }
    }
#pragma unroll
    for (int u = 0; u < 8; ++u)
        if (dst[u] >= 0) atomicAdd(&hist[dst[u] >> BSH], 1);
    __syncthreads();
    // exclusive scan of hist[0..MAXB) by wave 0 (cross-chunk carry included)
    if (tid < 64) {
        int carry = 0;
        for (int c = 0; c < MAXB / 64; ++c) {
            int idx = c * 64 + tid;
            int v = hist[idx];
            int orig = v;
            for (int off = 1; off < 64; off <<= 1) {
                int t = __shfl_up(v, off);
                if (tid >= off) v += t;
            }
            int ex = v - orig + carry;
            off0[idx] = ex;
            cur[idx] = ex;
            carry += __shfl(v, 63);
        }
    }
    __syncthreads();
    int* orow = offmat + (size_t)blockIdx.x * (nbuck + 1);
    for (int b = tid; b <= nbuck; b += 512) orow[b] = off0[b];
#pragma unroll
    for (int u = 0; u < 8; ++u) {
        int d = dst[u];
        if (d >= 0) {
            int b = d >> BSH;
            int slot = atomicAdd(&cur[b], 1);
            packed[t0 + slot] = src[u] | ((d & (BN - 1)) << 17);
        }
    }
}

// ============ Phase B: one 1024-thread block per bucket (staged, wave-shuffle scans) ============

__global__ __launch_bounds__(1024) void k_csr(const int* __restrict__ packed,
                                              const int* __restrict__ offmat,
                                              int* __restrict__ csr,
                                              int* __restrict__ rowptr,
                                              int* __restrict__ deg,
                                              float* __restrict__ dinv,
                                              int N, int nbuck, int nblkA) {
    __shared__ int stage[CAP];      // 48 KB
    __shared__ int startA[1024];    // 4 KB
    __shared__ int o1A[1024];       // 4 KB
    __shared__ int hcnt[BN];
    __shared__ int cur[BN];
    __shared__ int wsum[16];
    __shared__ int woff[4];
    int tid = threadIdx.x;
    int wid = tid >> 6, lane = tid & 63;
    int b = blockIdx.x;
    size_t base = (size_t)b * S;

    int len = 0, o1 = 0;
    if (tid < nblkA) {
        const int* orow = offmat + (size_t)tid * (nbuck + 1) + b;
        o1 = orow[0];
        len = orow[1] - o1;
    }
    o1A[tid] = o1;
    if (tid < BN) hcnt[tid] = 0;

    // inclusive wave-shuffle scan of run lengths (1024 entries, 16 waves)
    int v = len;
#pragma unroll
    for (int off = 1; off < 64; off <<= 1) {
        int t = __shfl_up(v, off);
        if (lane >= off) v += t;
    }
    if (lane == 63) wsum[wid] = v;
    __syncthreads();
    if (tid < 16) {
        int w = wsum[tid];
#pragma unroll
        for (int off = 1; off < 16; off <<= 1) {
            int t = __shfl_up(w, off);
            if (tid >= off) w += t;
        }
        wsum[tid] = w;   // inclusive wave totals
    }
    __syncthreads();
    int m = wsum[15];
    int incl = v + ((wid > 0) ? wsum[wid - 1] : 0);
    startA[tid] = incl - len;   // exclusive start
    __syncthreads();
    if (m > CAP) m = CAP;       // statistically impossible; prevents LDS OOB

    // thread-per-edge coalesced gather + histogram
    for (int i = tid; i < m; i += 1024) {
        int lo = 0, hi = 1023;
        while (lo < hi) {       // largest j with startA[j] <= i
            int mid = (lo + hi + 1) >> 1;
            if (startA[mid] <= i) lo = mid; else hi = mid - 1;
        }
        int p = packed[(size_t)lo * TILE + o1A[lo] + (i - startA[lo])];
        stage[i] = p;
        atomicAdd(&hcnt[p >> 17], 1);
    }
    __syncthreads();
    // wave-shuffle scan of hcnt (256 entries in first 4 waves)
    int v2 = (tid < BN) ? hcnt[tid] : 0;
    int s2 = v2;
#pragma unroll
    for (int off = 1; off < 64; off <<= 1) {
        int t = __shfl_up(s2, off);
        if (lane >= off) s2 += t;
    }
    if (tid < BN && lane == 63) wsum[wid] = s2;   // reuse wsum[0..3]
    __syncthreads();
    if (tid == 0) {
        int acc = 0;
#pragma unroll
        for (int k = 0; k < 4; ++k) { int t = wsum[k]; woff[k] = acc; acc += t; }
    }
    __syncthreads();
    if (tid < BN) {
        int ex = (s2 - v2) + woff[wid];
        cur[tid] = ex;
        int n = (b << BSH) + tid;
        if (n < N) {
            rowptr[n] = (int)base + ex;
            deg[n] = v2;
            dinv[n] = rsqrtf((float)v2 + 1.0f);   // +1 self-loop
        }
    }
    __syncthreads();
    // place
    for (int i = tid; i < m; i += 1024) {
        int p = stage[i];
        int slot = atomicAdd(&cur[p >> 17], 1);
        csr[base + slot] = p & 0x1FFFF;
    }
}

// ============ linear 1: y1h = half((x @ W1) * dinv)  [N,16] fp16 ============

__global__ __launch_bounds__(256) void k_lin1(const float* __restrict__ x,
                                              const float* __restrict__ W1,
                                              const float* __restrict__ dinv,
                                              __half* __restrict__ y1h, int N) {
    __shared__ float ws[NF * C1];
    __shared__ float xs[16 * 132];
    int tid = threadIdx.x;
    for (int t = tid; t < NF * C1; t += 256) ws[t] = W1[t];
    int n0 = blockIdx.x * 16;
    const float4* x4 = (const float4*)x;
    for (int t = tid; t < 16 * 32; t += 256) {
        int r = t >> 5, c = t & 31;
        int n = n0 + r;
        float4 v = (n < N) ? x4[(size_t)n * 32 + c] : make_float4(0.f, 0.f, 0.f, 0.f);
        float* d = &xs[r * 132 + c * 4];
        d[0] = v.x; d[1] = v.y; d[2] = v.z; d[3] = v.w;
    }
    __syncthreads();
    int r = tid >> 4, j = tid & 15;
    float acc = 0.0f;
#pragma unroll 4
    for (int k = 0; k < NF; ++k) acc += xs[r * 132 + k] * ws[k * C1 + j];
    int n = n0 + r;
    if (n < N) y1h[(size_t)n * C1 + j] = __float2half_rn(acc * dinv[n]);
}

// ============ fp16 gather (16-dim, f32 accum), 4 threads/node, 8B loads ============
// MODE 0: out = float4 agg = dinv*(self + sum)          (feeds pool_fc)
// MODE 1: out = 4x half  u  = relu(agg + b1)*dinv       (feeds 2nd gather)

template <int MODE>
__global__ __launch_bounds__(256) void k_gather_h(const int* __restrict__ rowptr,
                                                  const int* __restrict__ deg,
                                                  const int* __restrict__ csr,
                                                  const float* __restrict__ dinv,
                                                  const float* __restrict__ bias,
                                                  const uint2* __restrict__ yh,
                                                  void* __restrict__ outp, int N) {
    int tid = threadIdx.x;
    int j = tid & 3;                       // quarter-row (4 halfs)
    int n = blockIdx.x * 64 + (tid >> 2);
    if (n >= N) return;
    int k0 = rowptr[n];
    int k1 = k0 + deg[n];
    union U { uint2 u; __half2 h[2]; };
    U su; su.u = yh[(size_t)n * 4 + j];
    float2 sl = __half22float2(su.h[0]), shh = __half22float2(su.h[1]);
    float a0 = sl.x, a1 = sl.y, a2 = shh.x, a3 = shh.y;
    float b0 = 0.f, b1v = 0.f, b2 = 0.f, b3 = 0.f;
    int k = k0;
    for (; k + 3 < k1; k += 4) {
        int s0 = csr[k], s1 = csr[k + 1], s2 = csr[k + 2], s3 = csr[k + 3];
        U v0, v1, v2, v3;
        v0.u = yh[(size_t)s0 * 4 + j];
        v1.u = yh[(size_t)s1 * 4 + j];
        v2.u = yh[(size_t)s2 * 4 + j];
        v3.u = yh[(size_t)s3 * 4 + j];
        float2 l0 = __half22float2(v0.h[0]), h0 = __half22float2(v0.h[1]);
        float2 l1 = __half22float2(v1.h[0]), h1 = __half22float2(v1.h[1]);
        float2 l2 = __half22float2(v2.h[0]), h2 = __half22float2(v2.h[1]);
        float2 l3 = __half22float2(v3.h[0]), h3 = __half22float2(v3.h[1]);
        a0 += l0.x; a1 += l0.y; a2 += h0.x; a3 += h0.y;
        b0 += l1.x; b1v += l1.y; b2 += h1.x; b3 += h1.y;
        a0 += l2.x; a1 += l2.y; a2 += h2.x; a3 += h2.y;
        b0 += l3.x; b1v += l3.y; b2 += h3.x; b3 += h3.y;
    }
    for (; k < k1; ++k) {
        U v; v.u = yh[(size_t)csr[k] * 4 + j];
        float2 l = __half22float2(v.h[0]), h = __half22float2(v.h[1]);
        a0 += l.x; a1 += l.y; a2 += h.x; a3 += h.y;
    }
    float dn = dinv[n];
    float r0 = dn * (a0 + b0), r1 = dn * (a1 + b1v);
    float r2 = dn * (a2 + b2), r3 = dn * (a3 + b3);
    if (MODE == 0) {
        ((float4*)outp)[(size_t)n * 4 + j] = make_float4(r0, r1, r2, r3);
    } else {
        float4 bb = ((const float4*)bias)[j];
        U o;
        o.h[0] = __floats2half2_rn(fmaxf(r0 + bb.x, 0.0f) * dn, fmaxf(r1 + bb.y, 0.0f) * dn);
        o.h[1] = __floats2half2_rn(fmaxf(r2 + bb.z, 0.0f) * dn, fmaxf(r3 + bb.w, 0.0f) * dn);
        ((uint2*)outp)[(size_t)n * 4 + j] = o.u;
    }
}

// ============ pool + W2 + relu + FC fused (per graph; sorted batch) ============

__global__ __launch_bounds__(256) void k_pool_fc(const float* __restrict__ z,
                                                 const float* __restrict__ W2,
                                                 const float* __restrict__ b2,
                                                 const int* __restrict__ batch,
                                                 const float* __restrict__ Wfc,
                                                 const float* __restrict__ bfc,
                                                 float* __restrict__ out, int N, int G) {
    __shared__ float W2s[C1 * C2];
    int tid = threadIdx.x;
    for (int t = tid; t < C1 * C2; t += 256) W2s[t] = W2[t];

    int g = blockIdx.x;
    int lo = 0, hi = N;
    while (lo < hi) { int m = (lo + hi) >> 1; if (batch[m] < g) lo = m + 1; else hi = m; }
    int start = lo;
    lo = start; hi = N;
    while (lo < hi) { int m = (lo + hi) >> 1; if (batch[m] < g + 1) lo = m + 1; else hi = m; }
    int end = lo;
    __syncthreads();

    int i = tid & 31, r = tid >> 5;       // 8 node-groups x 32 output channels
    float bi = b2[i];
    float acc = 0.0f;
    for (int n = start + r; n < end; n += 8) {
        const float* zr = &z[(size_t)n * C1];
        float h = bi;
#pragma unroll
        for (int j = 0; j < C1; ++j) h += zr[j] * W2s[j * C2 + i];
        acc += fmaxf(h, 0.0f);
    }

    __shared__ float red[256];
    red[tid] = acc;
    __syncthreads();
    for (int s = 4; s >= 1; s >>= 1) {
        if (r < s) red[tid] += red[tid + s * 32];
        __syncthreads();
    }
    __shared__ float pooled[C2];
    if (tid < C2) {
        float cnt = (float)(end - start);
        pooled[tid] = red[tid] / fmaxf(cnt, 1.0f);
    }
    __syncthreads();
    if (tid < NCLS) {
        float a = bfc[tid];
#pragma unroll
        for (int j = 0; j < C2; ++j) a += pooled[j] * Wfc[j * NCLS + tid];
        out[g * NCLS + tid] = a;
    }
}

extern "C" void kernel_launch(void* const* d_in, const int* in_sizes, int n_in,
                              void* d_out, int out_size, void* d_ws, size_t ws_size,
                              hipStream_t stream) {
    const float* x    = (const float*)d_in[0];
    const int*   ei   = (const int*)d_in[1];
    const int*   batch= (const int*)d_in[2];
    const float* W1   = (const float*)d_in[3];
    const float* b1   = (const float*)d_in[4];
    const float* W2   = (const float*)d_in[5];
    const float* b2   = (const float*)d_in[6];
    const float* Wfc  = (const float*)d_in[7];
    const float* bfc  = (const float*)d_in[8];
    float* out = (float*)d_out;

    const int N = in_sizes[0] / NF;          // 100000
    const int E = in_sizes[1] / 2;           // 3200000
    const int G = out_size / NCLS;           // 256
    const int nbuck = (N + BN - 1) >> BSH;   // 391
    const int nblkA = (E + TILE - 1) / TILE; // 782

    char* p = (char*)d_ws;
    auto alloc = [&](size_t bytes) { char* q = p; p += (bytes + 63) & ~(size_t)63; return q; };
    int*     rowptr  = (int*)    alloc((size_t)N * 4);
    int*     deg     = (int*)    alloc((size_t)N * 4);
    float*   dinv    = (float*)  alloc((size_t)N * 4);
    int*     packed  = (int*)    alloc((size_t)nblkA * TILE * 4);         // 12.8 MB
    int*     offmat  = (int*)    alloc((size_t)nblkA * (nbuck + 1) * 4); // 1.2 MB
    int*     csr     = (int*)    alloc((size_t)nbuck * S * 4);           // 14.4 MB
    __half*  y1h     = (__half*) alloc((size_t)N * C1 * 2);
    __half*  uh      = (__half*) alloc((size_t)N * C1 * 2);
    float*   z       = (float*)  alloc((size_t)N * C1 * 4);

    const int B = 256;

    // --- CSR build: tile-local grouping (coalesced) + staged run-gather sort ---
    k_bin<<<nblkA, 512, 0, stream>>>(ei, packed, offmat, E, nbuck);
    k_csr<<<nbuck, 1024, 0, stream>>>(packed, offmat, csr, rowptr, deg, dinv,
                                      N, nbuck, nblkA);

    // --- layer 1 ---
    k_lin1<<<(N + 15) / 16, B, 0, stream>>>(x, W1, dinv, y1h, N);
    k_gather_h<1><<<(N + 63) / 64, B, 0, stream>>>(rowptr, deg, csr, dinv, b1,
                                                   (const uint2*)y1h, uh, N);
    // --- layer 2 aggregation (16-dim; W2 commuted into pool) ---
    k_gather_h<0><<<(N + 63) / 64, B, 0, stream>>>(rowptr, deg, csr, dinv, b1,
                                                   (const uint2*)uh, z, N);

    // --- pool + W2 + relu + FC ---
    k_pool_fc<<<G, B, 0, stream>>>(z, W2, b2, batch, Wfc, bfc, out, N, G);
}